// Round 2
// baseline (662.451 us; speedup 1.0000x reference)
//
#include <hip/hip_runtime.h>
#include <cstdint>
#include <cstddef>

// N=65536 samples, Din=256, Dout=768, fused K = 512 (=[h0|S])
#define NSAMP 65536
#define KDIM  512
#define MDIM  768

typedef __attribute__((ext_vector_type(8))) _Float16 f16x8;
typedef __attribute__((ext_vector_type(4))) float f32x4;

union H2U { _Float16 h; unsigned short u; };
__device__ __forceinline__ unsigned short f2h(float f) {
  H2U v; v.h = (_Float16)f; return v.u;
}
__device__ __forceinline__ float h2f(unsigned short u) {
  H2U v; v.u = u; return (float)v.h;
}

// ---------------- pack A = [h0 | h0+h1+h2] as f16 [N][512] ----------------
__global__ __launch_bounds__(256) void prep_A_kernel(const float* __restrict__ x,
                                                     unsigned short* __restrict__ A) {
  int gid = blockIdx.x * 256 + threadIdx.x;   // n*64 + cg
  int n  = gid >> 6;
  int cg = gid & 63;                           // group of 4 floats, c = cg*4
  const float4* xr = (const float4*)(x + (size_t)n * 768);
  float4 a = xr[cg];
  float4 b = xr[64 + cg];
  float4 c = xr[128 + cg];
  ushort4 lo, hi;
  lo.x = f2h(a.x); lo.y = f2h(a.y); lo.z = f2h(a.z); lo.w = f2h(a.w);
  hi.x = f2h(a.x + b.x + c.x); hi.y = f2h(a.y + b.y + c.y);
  hi.z = f2h(a.z + b.z + c.z); hi.w = f2h(a.w + b.w + c.w);
  unsigned short* Arow = A + (size_t)n * KDIM;
  *(ushort4*)(Arow + cg * 4) = lo;
  *(ushort4*)(Arow + 256 + cg * 4) = hi;
}

// ------------- fuse weights, stage 1: fp32 partials over j-chunks ----------
// M1[i][m] = sum_j (w2a-0.5w1a)[i][j] * (w2b-0.5w1b)[j][m]
// M2[i][m] = sum_j w1a[i][j]*(0.5w2b+0.25w1b)[j][m] + w2a[i][j]*(0.5w1b)[j][m]
// grid = 32 i-chunks x 3 m-chunks x 4 j-chunks = 384 blocks, 256 thr
// temp layout: [mat(2)][jc(4)][m(768)][i(256)] fp32
__global__ __launch_bounds__(256) void prep_B_partial(const float* __restrict__ w1a,
                                                      const float* __restrict__ w2a,
                                                      const float* __restrict__ w1b,
                                                      const float* __restrict__ w2b,
                                                      float* __restrict__ temp) {
  int b = blockIdx.x;
  int jc = b & 3;
  int rem = b >> 2;          // 0..95
  int mc = rem % 3;
  int ic = rem / 3;          // 0..31
  int t = threadIdx.x;
  int m = mc * 256 + t;
  int i0 = ic * 8;
  int j0 = jc * 192;
  __shared__ __align__(16) float sC[8][192];   // w2a - 0.5*w1a
  __shared__ __align__(16) float s1[8][192];   // w1a
  __shared__ __align__(16) float s2[8][192];   // w2a
  for (int idx = t; idx < 8 * 192; idx += 256) {
    int ii = idx / 192, jj = idx % 192;
    float a1 = w1a[(size_t)(i0 + ii) * 768 + j0 + jj];
    float a2 = w2a[(size_t)(i0 + ii) * 768 + j0 + jj];
    s1[ii][jj] = a1; s2[ii][jj] = a2; sC[ii][jj] = a2 - 0.5f * a1;
  }
  __syncthreads();
  float acc1[8] = {0,0,0,0,0,0,0,0};
  float acc2[8] = {0,0,0,0,0,0,0,0};
  const float* pb1 = w1b + (size_t)j0 * 768 + m;
  const float* pb2 = w2b + (size_t)j0 * 768 + m;
  for (int jb = 0; jb < 192; jb += 4) {
    float F[4], Gp[4], Hh[4];
#pragma unroll
    for (int u = 0; u < 4; ++u) {
      float b1 = pb1[(size_t)(jb + u) * 768];
      float b2 = pb2[(size_t)(jb + u) * 768];
      F[u]  = b2 - 0.5f * b1;
      Gp[u] = 0.5f * b2 + 0.25f * b1;
      Hh[u] = 0.5f * b1;
    }
#pragma unroll
    for (int ii = 0; ii < 8; ++ii) {
      f32x4 c  = *(const f32x4*)&sC[ii][jb];
      f32x4 a1 = *(const f32x4*)&s1[ii][jb];
      f32x4 a2 = *(const f32x4*)&s2[ii][jb];
#pragma unroll
      for (int u = 0; u < 4; ++u) {
        acc1[ii] += c[u] * F[u];
        acc2[ii] += a1[u] * Gp[u] + a2[u] * Hh[u];
      }
    }
  }
  float* t1 = temp + ((size_t)jc * 768 + m) * 256 + i0;
  float* t2 = temp + ((size_t)(4 + jc) * 768 + m) * 256 + i0;
#pragma unroll
  for (int ii = 0; ii < 8; ++ii) { t1[ii] = acc1[ii]; t2[ii] = acc2[ii]; }
}

// ------------- fuse weights, stage 2: reduce j-chunks -> Bt f16 ------------
// Bt[m][i] = M1[i][m], Bt[m][256+i] = M2[i][m]. Also zero BN stats.
__global__ __launch_bounds__(256) void prep_B_convert(const float* __restrict__ temp,
                                                      unsigned short* __restrict__ Bt,
                                                      float* __restrict__ stats) {
  int idx = blockIdx.x * 256 + threadIdx.x;  // 0..196607
  int i = idx & 255;
  int m = idx >> 8;
  const float* t1 = temp + (size_t)m * 256 + i;
  const float* t2 = temp + ((size_t)4 * 768 + m) * 256 + i;
  float v1 = 0.f, v2 = 0.f;
#pragma unroll
  for (int jc = 0; jc < 4; ++jc) {
    v1 += t1[(size_t)jc * 768 * 256];
    v2 += t2[(size_t)jc * 768 * 256];
  }
  Bt[(size_t)m * KDIM + i]       = f2h(v1);
  Bt[(size_t)m * KDIM + 256 + i] = f2h(v2);
  if (idx < 1536) stats[idx] = 0.f;
}

// ---------------- main GEMM: out_pre = A @ B, + BN partial stats ------------
// NO-LDS direct-to-register MFMA kernel.
// Post-mortem of the LDS version: MfmaUtil 17 / VALUBusy 14 / HBM 37 /
// Occ 27 -> latency-bound; the vmcnt(0)+barrier drain per BK-step had only
// ~155 MFMA cycles to amortize a ~500-900 cyc load return. Here: B (0.75 MiB)
// is L2-resident, A has only 2x in-block reuse, and K=512 f16 spans 1024 B
// per row -> the WHOLE K range folds into the 13-bit global_load offset
// immediate. So each wave loads its MFMA fragments straight from global with
// 8 base addresses (4 A rows, 4 B rows), zero barriers, zero LDS. A manual
// 2-deep register pipeline (static names) lets the compiler keep 8 loads in
// flight under each 16-MFMA cluster with counted vmcnt.
// XCD remap kept: 3072 blocks = 8*384; each XCD owns 64 contiguous row-panels
// so a panel's 6 column-tiles hit the same 4-MiB L2.
template <bool F16OUT>
__global__ __launch_bounds__(256) void gemm_kernel(const unsigned short* __restrict__ A,
                                                   const unsigned short* __restrict__ Bt,
                                                   float* __restrict__ outf,
                                                   unsigned short* __restrict__ outh,
                                                   float* __restrict__ stats) {
  int bid = blockIdx.x;
  int swz = (bid & 7) * 384 + (bid >> 3);  // bijective: 3072 % 8 == 0
  int bm  = swz % 6;             // col tile (M=768 -> 6)
  int bn  = swz / 6;             // row tile (N=65536 -> 512)
  int tid  = threadIdx.x;
  int wid  = tid >> 6;
  int lane = tid & 63;
  int quad = lane >> 4;
  int l15  = lane & 15;
  int wave_r = wid >> 1;         // 0..1
  int wave_c = wid & 1;          // 0..1

  size_t row0 = (size_t)bn * 128;
  int    col0 = bm * 128;

  f32x4 acc[4][4];
#pragma unroll
  for (int i = 0; i < 4; ++i)
#pragma unroll
    for (int j = 0; j < 4; ++j) acc[i][j] = (f32x4)(0.f);

  // per-lane fragment base addresses; rb/cb step = 16 rows * 512 shorts,
  // k step = 32 shorts = 64 B -> folds into the 13-bit offset immediate.
  const unsigned short* baseA = A  + (row0 + wave_r * 64 + l15) * KDIM + quad * 8;
  const unsigned short* baseB = Bt + (size_t)(col0 + wave_c * 64 + l15) * KDIM + quad * 8;

#define LOADSET(aF, bF, kk)                                                        \
  do {                                                                             \
    _Pragma("unroll")                                                              \
    for (int rb = 0; rb < 4; ++rb)                                                 \
      aF[rb] = *(const f16x8*)(baseA + (size_t)rb * (16 * KDIM) + (kk));           \
    _Pragma("unroll")                                                              \
    for (int cb = 0; cb < 4; ++cb)                                                 \
      bF[cb] = *(const f16x8*)(baseB + (size_t)cb * (16 * KDIM) + (kk));           \
  } while (0)

#define MFMASET(aF, bF)                                                            \
  do {                                                                             \
    _Pragma("unroll")                                                              \
    for (int rb = 0; rb < 4; ++rb)                                                 \
      _Pragma("unroll")                                                            \
      for (int cb = 0; cb < 4; ++cb)                                               \
        acc[rb][cb] =                                                              \
            __builtin_amdgcn_mfma_f32_16x16x32_f16(aF[rb], bF[cb], acc[rb][cb],    \
                                                   0, 0, 0);                       \
  } while (0)

  f16x8 a0[4], b0[4], a1[4], b1[4];
  LOADSET(a0, b0, 0);
#pragma unroll
  for (int k0 = 0; k0 < KDIM; k0 += 64) {
    LOADSET(a1, b1, k0 + 32);      // next fragments in flight under MFMAs
    MFMASET(a0, b0);
    if (k0 + 64 < KDIM) LOADSET(a0, b0, k0 + 64);
    MFMASET(a1, b1);
  }
#undef LOADSET
#undef MFMASET

  // epilogue: store out_pre + per-column partial sums for BN (from fp32 accs)
#pragma unroll
  for (int cb = 0; cb < 4; ++cb) {
    int col = col0 + wave_c * 64 + cb * 16 + l15;
    float s1 = 0.f, s2 = 0.f;
#pragma unroll
    for (int rb = 0; rb < 4; ++rb) {
      size_t rg = row0 + wave_r * 64 + rb * 16 + quad * 4;
#pragma unroll
      for (int reg = 0; reg < 4; ++reg) {
        float v = acc[rb][cb][reg];
        if (F16OUT) outh[(rg + reg) * MDIM + col] = f2h(v);
        else        outf[(rg + reg) * MDIM + col] = v;
        s1 += v;
        s2 += v * v;
      }
    }
    s1 += __shfl_xor(s1, 16); s1 += __shfl_xor(s1, 32);
    s2 += __shfl_xor(s2, 16); s2 += __shfl_xor(s2, 32);
    if (quad == 0) {
      atomicAdd(&stats[col], s1);
      atomicAdd(&stats[768 + col], s2);
    }
  }
}

// ---------------- BN stats -> scale/shift ----------------------------------
__global__ void finalize_stats(const float* __restrict__ stats, const float* __restrict__ gamma,
                               const float* __restrict__ beta, float* __restrict__ ss) {
  int c = threadIdx.x;
  if (c < 768) {
    const float inv_n = 1.0f / 65536.0f;
    float mean = stats[c] * inv_n;
    float ex2  = stats[768 + c] * inv_n;
    float var  = ex2 - mean * mean;
    float scale = gamma[c] * rsqrtf(var + 1e-5f);
    ss[c]       = scale;
    ss[768 + c] = beta[c] - mean * scale;
  }
}

// ---------------- BN apply + sigmoid: f16 staging -> f32 out ---------------
__global__ __launch_bounds__(256) void bn_sigmoid_h(const unsigned short* __restrict__ outpre,
                                                    const float* __restrict__ ss,
                                                    float* __restrict__ out) {
  int idx = blockIdx.x * 256 + threadIdx.x;  // group of 8 halves
  int cg  = (idx % 96) * 8;
  f16x8 h = *(const f16x8*)(outpre + (size_t)idx * 8);
  float4 sc0 = *(const float4*)&ss[cg];
  float4 sc1 = *(const float4*)&ss[cg + 4];
  float4 sh0 = *(const float4*)&ss[768 + cg];
  float4 sh1 = *(const float4*)&ss[768 + cg + 4];
  float4 r0, r1;
  r0.x = 1.f / (1.f + __expf(-((float)h[0] * sc0.x + sh0.x)));
  r0.y = 1.f / (1.f + __expf(-((float)h[1] * sc0.y + sh0.y)));
  r0.z = 1.f / (1.f + __expf(-((float)h[2] * sc0.z + sh0.z)));
  r0.w = 1.f / (1.f + __expf(-((float)h[3] * sc0.w + sh0.w)));
  r1.x = 1.f / (1.f + __expf(-((float)h[4] * sc1.x + sh1.x)));
  r1.y = 1.f / (1.f + __expf(-((float)h[5] * sc1.y + sh1.y)));
  r1.z = 1.f / (1.f + __expf(-((float)h[6] * sc1.z + sh1.z)));
  r1.w = 1.f / (1.f + __expf(-((float)h[7] * sc1.w + sh1.w)));
  ((float4*)out)[(size_t)idx * 2]     = r0;
  ((float4*)out)[(size_t)idx * 2 + 1] = r1;
}

// ---------------- BN apply + sigmoid, in place fp32 (fallback) -------------
__global__ __launch_bounds__(256) void bn_sigmoid_f(float* __restrict__ out,
                                                    const float* __restrict__ ss) {
  int idx = blockIdx.x * 256 + threadIdx.x;  // float4 index
  int cg  = (idx % 192) * 4;
  float4 v  = ((const float4*)out)[idx];
  float4 sc = *(const float4*)&ss[cg];
  float4 sh = *(const float4*)&ss[768 + cg];
  v.x = 1.f / (1.f + __expf(-(v.x * sc.x + sh.x)));
  v.y = 1.f / (1.f + __expf(-(v.y * sc.y + sh.y)));
  v.z = 1.f / (1.f + __expf(-(v.z * sc.z + sh.z)));
  v.w = 1.f / (1.f + __expf(-(v.w * sc.w + sh.w)));
  ((float4*)out)[idx] = v;
}

extern "C" void kernel_launch(void* const* d_in, const int* in_sizes, int n_in,
                              void* d_out, int out_size, void* d_ws, size_t ws_size,
                              hipStream_t stream) {
  const float* x     = (const float*)d_in[0];
  const float* w1a   = (const float*)d_in[1];
  const float* w2a   = (const float*)d_in[2];
  const float* w1b   = (const float*)d_in[3];
  const float* w2b   = (const float*)d_in[4];
  const float* gamma = (const float*)d_in[5];
  const float* beta  = (const float*)d_in[6];
  float* out = (float*)d_out;

  // workspace layout
  size_t offA     = 0;
  size_t offBt    = offA + (size_t)NSAMP * KDIM * 2;            // 64 MiB
  size_t offTemp  = offBt + (size_t)MDIM * KDIM * 2;            // +0.75 MiB
  size_t offStats = offTemp + (size_t)2 * 4 * 768 * 256 * 4;    // +6 MiB
  size_t offSS    = offStats + 1536 * 4;
  size_t offOut   = (offSS + 1536 * 4 + 255) & ~(size_t)255;
  size_t needF16  = offOut + (size_t)NSAMP * MDIM * 2;          // ~167 MiB

  unsigned short* A    = (unsigned short*)((char*)d_ws + offA);
  unsigned short* Bt   = (unsigned short*)((char*)d_ws + offBt);
  float* temp          = (float*)((char*)d_ws + offTemp);
  float* stats         = (float*)((char*)d_ws + offStats);
  float* ss            = (float*)((char*)d_ws + offSS);
  unsigned short* oh   = (unsigned short*)((char*)d_ws + offOut);
  bool f16stage = ws_size >= needF16;

  prep_A_kernel<<<NSAMP * 64 / 256, 256, 0, stream>>>(x, A);
  prep_B_partial<<<384, 256, 0, stream>>>(w1a, w2a, w1b, w2b, temp);
  prep_B_convert<<<768, 256, 0, stream>>>(temp, Bt, stats);
  if (f16stage) {
    gemm_kernel<true><<<(NSAMP / 128) * (MDIM / 128), 256, 0, stream>>>(A, Bt, nullptr, oh, stats);
    finalize_stats<<<1, 768, 0, stream>>>(stats, gamma, beta, ss);
    bn_sigmoid_h<<<(size_t)NSAMP * MDIM / 8 / 256, 256, 0, stream>>>(oh, ss, out);
  } else {
    gemm_kernel<false><<<(NSAMP / 128) * (MDIM / 128), 256, 0, stream>>>(A, Bt, out, nullptr, stats);
    finalize_stats<<<1, 768, 0, stream>>>(stats, gamma, beta, ss);
    bn_sigmoid_f<<<(size_t)NSAMP * MDIM / 4 / 256, 256, 0, stream>>>(out, ss);
  }
}

// Round 3
// 572.636 us; speedup vs baseline: 1.1568x; 1.1568x over previous
//
#include <hip/hip_runtime.h>
#include <cstdint>
#include <cstddef>

// N=65536 samples, Din=256, Dout=768, fused K = 512 (=[h0|S])
#define NSAMP 65536
#define KDIM  512
#define MDIM  768

typedef __attribute__((ext_vector_type(8))) _Float16 f16x8;
typedef __attribute__((ext_vector_type(4))) float f32x4;

union H2U { _Float16 h; unsigned short u; };
__device__ __forceinline__ unsigned short f2h(float f) {
  H2U v; v.h = (_Float16)f; return v.u;
}
__device__ __forceinline__ float h2f(unsigned short u) {
  H2U v; v.u = u; return (float)v.h;
}

// ---------------- pack A = [h0 | h0+h1+h2] as f16 [N][512] ----------------
__global__ __launch_bounds__(256) void prep_A_kernel(const float* __restrict__ x,
                                                     unsigned short* __restrict__ A) {
  int gid = blockIdx.x * 256 + threadIdx.x;   // n*64 + cg
  int n  = gid >> 6;
  int cg = gid & 63;                           // group of 4 floats, c = cg*4
  const float4* xr = (const float4*)(x + (size_t)n * 768);
  float4 a = xr[cg];
  float4 b = xr[64 + cg];
  float4 c = xr[128 + cg];
  ushort4 lo, hi;
  lo.x = f2h(a.x); lo.y = f2h(a.y); lo.z = f2h(a.z); lo.w = f2h(a.w);
  hi.x = f2h(a.x + b.x + c.x); hi.y = f2h(a.y + b.y + c.y);
  hi.z = f2h(a.z + b.z + c.z); hi.w = f2h(a.w + b.w + c.w);
  unsigned short* Arow = A + (size_t)n * KDIM;
  *(ushort4*)(Arow + cg * 4) = lo;
  *(ushort4*)(Arow + 256 + cg * 4) = hi;
}

// ------------- fuse weights, stage 1: fp32 partials over j-chunks ----------
__global__ __launch_bounds__(256) void prep_B_partial(const float* __restrict__ w1a,
                                                      const float* __restrict__ w2a,
                                                      const float* __restrict__ w1b,
                                                      const float* __restrict__ w2b,
                                                      float* __restrict__ temp) {
  int b = blockIdx.x;
  int jc = b & 3;
  int rem = b >> 2;          // 0..95
  int mc = rem % 3;
  int ic = rem / 3;          // 0..31
  int t = threadIdx.x;
  int m = mc * 256 + t;
  int i0 = ic * 8;
  int j0 = jc * 192;
  __shared__ __align__(16) float sC[8][192];   // w2a - 0.5*w1a
  __shared__ __align__(16) float s1[8][192];   // w1a
  __shared__ __align__(16) float s2[8][192];   // w2a
  for (int idx = t; idx < 8 * 192; idx += 256) {
    int ii = idx / 192, jj = idx % 192;
    float a1 = w1a[(size_t)(i0 + ii) * 768 + j0 + jj];
    float a2 = w2a[(size_t)(i0 + ii) * 768 + j0 + jj];
    s1[ii][jj] = a1; s2[ii][jj] = a2; sC[ii][jj] = a2 - 0.5f * a1;
  }
  __syncthreads();
  float acc1[8] = {0,0,0,0,0,0,0,0};
  float acc2[8] = {0,0,0,0,0,0,0,0};
  const float* pb1 = w1b + (size_t)j0 * 768 + m;
  const float* pb2 = w2b + (size_t)j0 * 768 + m;
  for (int jb = 0; jb < 192; jb += 4) {
    float F[4], Gp[4], Hh[4];
#pragma unroll
    for (int u = 0; u < 4; ++u) {
      float b1 = pb1[(size_t)(jb + u) * 768];
      float b2 = pb2[(size_t)(jb + u) * 768];
      F[u]  = b2 - 0.5f * b1;
      Gp[u] = 0.5f * b2 + 0.25f * b1;
      Hh[u] = 0.5f * b1;
    }
#pragma unroll
    for (int ii = 0; ii < 8; ++ii) {
      f32x4 c  = *(const f32x4*)&sC[ii][jb];
      f32x4 a1 = *(const f32x4*)&s1[ii][jb];
      f32x4 a2 = *(const f32x4*)&s2[ii][jb];
#pragma unroll
      for (int u = 0; u < 4; ++u) {
        acc1[ii] += c[u] * F[u];
        acc2[ii] += a1[u] * Gp[u] + a2[u] * Hh[u];
      }
    }
  }
  float* t1 = temp + ((size_t)jc * 768 + m) * 256 + i0;
  float* t2 = temp + ((size_t)(4 + jc) * 768 + m) * 256 + i0;
#pragma unroll
  for (int ii = 0; ii < 8; ++ii) { t1[ii] = acc1[ii]; t2[ii] = acc2[ii]; }
}

// ------------- fuse weights, stage 2: reduce j-chunks -> Bt f16 ------------
__global__ __launch_bounds__(256) void prep_B_convert(const float* __restrict__ temp,
                                                      unsigned short* __restrict__ Bt,
                                                      float* __restrict__ stats) {
  int idx = blockIdx.x * 256 + threadIdx.x;  // 0..196607
  int i = idx & 255;
  int m = idx >> 8;
  const float* t1 = temp + (size_t)m * 256 + i;
  const float* t2 = temp + ((size_t)4 * 768 + m) * 256 + i;
  float v1 = 0.f, v2 = 0.f;
#pragma unroll
  for (int jc = 0; jc < 4; ++jc) {
    v1 += t1[(size_t)jc * 768 * 256];
    v2 += t2[(size_t)jc * 768 * 256];
  }
  Bt[(size_t)m * KDIM + i]       = f2h(v1);
  Bt[(size_t)m * KDIM + 256 + i] = f2h(v2);
  if (idx < 1536) stats[idx] = 0.f;
}

// ---------------- main GEMM: out_pre = A @ B, + BN partial stats ------------
// 128x128 tile, BK=64, 4 waves, mfma 16x16x32 f16, XOR-swizzled LDS (r1,
// verified) + DOUBLE-BUFFERED staging with counted vmcnt (T3/T4):
//   prologue: stage tile0 -> buf0
//   loop:     stage tile t+1 -> buf^1; s_waitcnt vmcnt(8) (tile t landed,
//             t+1's 8 loads stay in flight ACROSS the barrier); s_barrier;
//             MFMA from buf; s_barrier (readers done before buf is re-staged)
// This removes the structural vmcnt(0)+barrier drain that left the r1 kernel
// 95% stalled (MfmaUtil 17, VALUBusy 14, HBM 37 -> all low = latency-bound).
// r2's no-LDS variant proved the XCD swizzle gets A fetched ~once (43.7 MB)
// but divergent per-lane fragment loads are TA-bound (16 lines/instr) -> keep
// the coalesced global_load_lds front end.
template <bool F16OUT>
__global__ __launch_bounds__(256) void gemm_kernel(const unsigned short* __restrict__ A,
                                                   const unsigned short* __restrict__ Bt,
                                                   float* __restrict__ outf,
                                                   unsigned short* __restrict__ outh,
                                                   float* __restrict__ stats) {
  __shared__ __align__(16) unsigned short As[2 * 128 * 64];
  __shared__ __align__(16) unsigned short Bs[2 * 128 * 64];

  int bid = blockIdx.x;
  int swz = (bid & 7) * 384 + (bid >> 3);  // bijective: 3072 % 8 == 0
  int bm  = swz % 6;             // col tile (M=768 -> 6)
  int bn  = swz / 6;             // row tile (N=65536 -> 512)
  int tid  = threadIdx.x;
  int wid  = tid >> 6;
  int lane = tid & 63;
  int quad = lane >> 4;
  int l15  = lane & 15;
  int wave_r = wid >> 1;         // 0..1
  int wave_c = wid & 1;          // 0..1

  size_t row0 = (size_t)bn * 128;
  int    col0 = bm * 128;

  f32x4 acc[4][4];
#pragma unroll
  for (int i = 0; i < 4; ++i)
#pragma unroll
    for (int j = 0; j < 4; ++j) acc[i][j] = (f32x4)(0.f);

  int rsub = lane >> 3;          // row within the wave's 8-row staging group
  int ssw  = (lane & 7) ^ rsub;  // pre-swizzled source slot (16-B units)

  // Wave-constant staging bases; (kk) folds into the 13-bit offset immediate.
  const unsigned short* gA0 = A  + (row0 + wid * 8 + rsub) * KDIM + ssw * 8;
  const unsigned short* gB0 = Bt + (size_t)(col0 + wid * 8 + rsub) * KDIM + ssw * 8;

#define STAGE(buf, kk)                                                              \
  do {                                                                              \
    _Pragma("unroll")                                                               \
    for (int i = 0; i < 4; ++i) {                                                   \
      int rl = i * 32 + wid * 8;                                                    \
      const unsigned short* gA = gA0 + (size_t)i * (32 * KDIM) + (kk);              \
      const unsigned short* gB = gB0 + (size_t)i * (32 * KDIM) + (kk);              \
      unsigned short* lA = As + (buf) * 8192 + rl * 64;                             \
      unsigned short* lB = Bs + (buf) * 8192 + rl * 64;                             \
      __builtin_amdgcn_global_load_lds(                                             \
          (const __attribute__((address_space(1))) void*)(uintptr_t)gA,             \
          (__attribute__((address_space(3))) void*)(uint32_t)(uintptr_t)lA, 16, 0, 0); \
      __builtin_amdgcn_global_load_lds(                                             \
          (const __attribute__((address_space(1))) void*)(uintptr_t)gB,             \
          (__attribute__((address_space(3))) void*)(uint32_t)(uintptr_t)lB, 16, 0, 0); \
    }                                                                               \
  } while (0)

#define COMPUTE(buf)                                                                \
  do {                                                                              \
    _Pragma("unroll")                                                               \
    for (int ks = 0; ks < 2; ++ks) {                                                \
      f16x8 a[4], b[4];                                                             \
      _Pragma("unroll")                                                             \
      for (int rb = 0; rb < 4; ++rb) {                                              \
        int r  = wave_r * 64 + rb * 16 + l15;                                       \
        int sl = (ks * 4 + quad) ^ (l15 & 7);                                       \
        a[rb] = *(const f16x8*)&As[(buf) * 8192 + r * 64 + sl * 8];                 \
      }                                                                             \
      _Pragma("unroll")                                                             \
      for (int cb = 0; cb < 4; ++cb) {                                              \
        int r  = wave_c * 64 + cb * 16 + l15;                                       \
        int sl = (ks * 4 + quad) ^ (l15 & 7);                                       \
        b[cb] = *(const f16x8*)&Bs[(buf) * 8192 + r * 64 + sl * 8];                 \
      }                                                                             \
      __builtin_amdgcn_s_setprio(1);                                               \
      _Pragma("unroll")                                                             \
      for (int rb = 0; rb < 4; ++rb)                                                \
        _Pragma("unroll")                                                           \
        for (int cb = 0; cb < 4; ++cb)                                              \
          acc[rb][cb] = __builtin_amdgcn_mfma_f32_16x16x32_f16(a[rb], b[cb],        \
                                                               acc[rb][cb], 0, 0, 0); \
      __builtin_amdgcn_s_setprio(0);                                               \
    }                                                                               \
  } while (0)

  STAGE(0, 0);
#pragma unroll
  for (int tt = 0; tt < 4; ++tt) {
    const int k0 = tt * 128;
    // even tile (k0) lives in buf0
    STAGE(1, k0 + 64);
    asm volatile("s_waitcnt vmcnt(8)" ::: "memory");
    __builtin_amdgcn_s_barrier();
    COMPUTE(0);
    __builtin_amdgcn_s_barrier();
    // odd tile (k0+64) lives in buf1
    if (tt < 3) {
      STAGE(0, k0 + 128);
      asm volatile("s_waitcnt vmcnt(8)" ::: "memory");
    } else {
      asm volatile("s_waitcnt vmcnt(0)" ::: "memory");
    }
    __builtin_amdgcn_s_barrier();
    COMPUTE(1);
    __builtin_amdgcn_s_barrier();
  }
#undef STAGE
#undef COMPUTE

  // epilogue: store out_pre + per-column partial sums for BN (from fp32 accs)
#pragma unroll
  for (int cb = 0; cb < 4; ++cb) {
    int col = col0 + wave_c * 64 + cb * 16 + l15;
    float s1 = 0.f, s2 = 0.f;
#pragma unroll
    for (int rb = 0; rb < 4; ++rb) {
      size_t rg = row0 + wave_r * 64 + rb * 16 + quad * 4;
#pragma unroll
      for (int reg = 0; reg < 4; ++reg) {
        float v = acc[rb][cb][reg];
        if (F16OUT) outh[(rg + reg) * MDIM + col] = f2h(v);
        else        outf[(rg + reg) * MDIM + col] = v;
        s1 += v;
        s2 += v * v;
      }
    }
    s1 += __shfl_xor(s1, 16); s1 += __shfl_xor(s1, 32);
    s2 += __shfl_xor(s2, 16); s2 += __shfl_xor(s2, 32);
    if (quad == 0) {
      atomicAdd(&stats[col], s1);
      atomicAdd(&stats[768 + col], s2);
    }
  }
}

// ---------------- BN stats -> scale/shift ----------------------------------
__global__ void finalize_stats(const float* __restrict__ stats, const float* __restrict__ gamma,
                               const float* __restrict__ beta, float* __restrict__ ss) {
  int c = threadIdx.x;
  if (c < 768) {
    const float inv_n = 1.0f / 65536.0f;
    float mean = stats[c] * inv_n;
    float ex2  = stats[768 + c] * inv_n;
    float var  = ex2 - mean * mean;
    float scale = gamma[c] * rsqrtf(var + 1e-5f);
    ss[c]       = scale;
    ss[768 + c] = beta[c] - mean * scale;
  }
}

// ---------------- BN apply + sigmoid: f16 staging -> f32 out ---------------
__global__ __launch_bounds__(256) void bn_sigmoid_h(const unsigned short* __restrict__ outpre,
                                                    const float* __restrict__ ss,
                                                    float* __restrict__ out) {
  int idx = blockIdx.x * 256 + threadIdx.x;  // group of 8 halves
  int cg  = (idx % 96) * 8;
  f16x8 h = *(const f16x8*)(outpre + (size_t)idx * 8);
  float4 sc0 = *(const float4*)&ss[cg];
  float4 sc1 = *(const float4*)&ss[cg + 4];
  float4 sh0 = *(const float4*)&ss[768 + cg];
  float4 sh1 = *(const float4*)&ss[768 + cg + 4];
  float4 r0, r1;
  r0.x = 1.f / (1.f + __expf(-((float)h[0] * sc0.x + sh0.x)));
  r0.y = 1.f / (1.f + __expf(-((float)h[1] * sc0.y + sh0.y)));
  r0.z = 1.f / (1.f + __expf(-((float)h[2] * sc0.z + sh0.z)));
  r0.w = 1.f / (1.f + __expf(-((float)h[3] * sc0.w + sh0.w)));
  r1.x = 1.f / (1.f + __expf(-((float)h[4] * sc1.x + sh1.x)));
  r1.y = 1.f / (1.f + __expf(-((float)h[5] * sc1.y + sh1.y)));
  r1.z = 1.f / (1.f + __expf(-((float)h[6] * sc1.z + sh1.z)));
  r1.w = 1.f / (1.f + __expf(-((float)h[7] * sc1.w + sh1.w)));
  ((float4*)out)[(size_t)idx * 2]     = r0;
  ((float4*)out)[(size_t)idx * 2 + 1] = r1;
}

// ---------------- BN apply + sigmoid, in place fp32 (fallback) -------------
__global__ __launch_bounds__(256) void bn_sigmoid_f(float* __restrict__ out,
                                                    const float* __restrict__ ss) {
  int idx = blockIdx.x * 256 + threadIdx.x;  // float4 index
  int cg  = (idx % 192) * 4;
  float4 v  = ((const float4*)out)[idx];
  float4 sc = *(const float4*)&ss[cg];
  float4 sh = *(const float4*)&ss[768 + cg];
  v.x = 1.f / (1.f + __expf(-(v.x * sc.x + sh.x)));
  v.y = 1.f / (1.f + __expf(-(v.y * sc.y + sh.y)));
  v.z = 1.f / (1.f + __expf(-(v.z * sc.z + sh.z)));
  v.w = 1.f / (1.f + __expf(-(v.w * sc.w + sh.w)));
  ((float4*)out)[idx] = v;
}

extern "C" void kernel_launch(void* const* d_in, const int* in_sizes, int n_in,
                              void* d_out, int out_size, void* d_ws, size_t ws_size,
                              hipStream_t stream) {
  const float* x     = (const float*)d_in[0];
  const float* w1a   = (const float*)d_in[1];
  const float* w2a   = (const float*)d_in[2];
  const float* w1b   = (const float*)d_in[3];
  const float* w2b   = (const float*)d_in[4];
  const float* gamma = (const float*)d_in[5];
  const float* beta  = (const float*)d_in[6];
  float* out = (float*)d_out;

  // workspace layout
  size_t offA     = 0;
  size_t offBt    = offA + (size_t)NSAMP * KDIM * 2;            // 64 MiB
  size_t offTemp  = offBt + (size_t)MDIM * KDIM * 2;            // +0.75 MiB
  size_t offStats = offTemp + (size_t)2 * 4 * 768 * 256 * 4;    // +6 MiB
  size_t offSS    = offStats + 1536 * 4;
  size_t offOut   = (offSS + 1536 * 4 + 255) & ~(size_t)255;
  size_t needF16  = offOut + (size_t)NSAMP * MDIM * 2;          // ~167 MiB

  unsigned short* A    = (unsigned short*)((char*)d_ws + offA);
  unsigned short* Bt   = (unsigned short*)((char*)d_ws + offBt);
  float* temp          = (float*)((char*)d_ws + offTemp);
  float* stats         = (float*)((char*)d_ws + offStats);
  float* ss            = (float*)((char*)d_ws + offSS);
  unsigned short* oh   = (unsigned short*)((char*)d_ws + offOut);
  bool f16stage = ws_size >= needF16;

  prep_A_kernel<<<NSAMP * 64 / 256, 256, 0, stream>>>(x, A);
  prep_B_partial<<<384, 256, 0, stream>>>(w1a, w2a, w1b, w2b, temp);
  prep_B_convert<<<768, 256, 0, stream>>>(temp, Bt, stats);
  if (f16stage) {
    gemm_kernel<true><<<(NSAMP / 128) * (MDIM / 128), 256, 0, stream>>>(A, Bt, nullptr, oh, stats);
    finalize_stats<<<1, 768, 0, stream>>>(stats, gamma, beta, ss);
    bn_sigmoid_h<<<(size_t)NSAMP * MDIM / 8 / 256, 256, 0, stream>>>(oh, ss, out);
  } else {
    gemm_kernel<false><<<(NSAMP / 128) * (MDIM / 128), 256, 0, stream>>>(A, Bt, out, nullptr, stats);
    finalize_stats<<<1, 768, 0, stream>>>(stats, gamma, beta, ss);
    bn_sigmoid_f<<<(size_t)NSAMP * MDIM / 4 / 256, 256, 0, stream>>>(out, ss);
  }
}

// Round 4
// 570.916 us; speedup vs baseline: 1.1603x; 1.0030x over previous
//
#include <hip/hip_runtime.h>
#include <cstdint>
#include <cstddef>

// N=65536 samples, Din=256, Dout=768, fused K = 512 (=[h0|S])
#define NSAMP 65536
#define KDIM  512
#define MDIM  768

typedef __attribute__((ext_vector_type(8))) _Float16 f16x8;
typedef __attribute__((ext_vector_type(4))) float f32x4;

union H2U { _Float16 h; unsigned short u; };
__device__ __forceinline__ unsigned short f2h(float f) {
  H2U v; v.h = (_Float16)f; return v.u;
}
__device__ __forceinline__ float h2f(unsigned short u) {
  H2U v; v.u = u; return (float)v.h;
}

// ---------------- pack A = [h0 | h0+h1+h2] as f16 [N][512] ----------------
__global__ __launch_bounds__(256) void prep_A_kernel(const float* __restrict__ x,
                                                     unsigned short* __restrict__ A) {
  int gid = blockIdx.x * 256 + threadIdx.x;   // n*64 + cg
  int n  = gid >> 6;
  int cg = gid & 63;                           // group of 4 floats, c = cg*4
  const float4* xr = (const float4*)(x + (size_t)n * 768);
  float4 a = xr[cg];
  float4 b = xr[64 + cg];
  float4 c = xr[128 + cg];
  ushort4 lo, hi;
  lo.x = f2h(a.x); lo.y = f2h(a.y); lo.z = f2h(a.z); lo.w = f2h(a.w);
  hi.x = f2h(a.x + b.x + c.x); hi.y = f2h(a.y + b.y + c.y);
  hi.z = f2h(a.z + b.z + c.z); hi.w = f2h(a.w + b.w + c.w);
  unsigned short* Arow = A + (size_t)n * KDIM;
  *(ushort4*)(Arow + cg * 4) = lo;
  *(ushort4*)(Arow + 256 + cg * 4) = hi;
}

// ------------- fuse weights, stage 1: fp32 partials over j-chunks ----------
__global__ __launch_bounds__(256) void prep_B_partial(const float* __restrict__ w1a,
                                                      const float* __restrict__ w2a,
                                                      const float* __restrict__ w1b,
                                                      const float* __restrict__ w2b,
                                                      float* __restrict__ temp) {
  int b = blockIdx.x;
  int jc = b & 3;
  int rem = b >> 2;          // 0..95
  int mc = rem % 3;
  int ic = rem / 3;          // 0..31
  int t = threadIdx.x;
  int m = mc * 256 + t;
  int i0 = ic * 8;
  int j0 = jc * 192;
  __shared__ __align__(16) float sC[8][192];   // w2a - 0.5*w1a
  __shared__ __align__(16) float s1[8][192];   // w1a
  __shared__ __align__(16) float s2[8][192];   // w2a
  for (int idx = t; idx < 8 * 192; idx += 256) {
    int ii = idx / 192, jj = idx % 192;
    float a1 = w1a[(size_t)(i0 + ii) * 768 + j0 + jj];
    float a2 = w2a[(size_t)(i0 + ii) * 768 + j0 + jj];
    s1[ii][jj] = a1; s2[ii][jj] = a2; sC[ii][jj] = a2 - 0.5f * a1;
  }
  __syncthreads();
  float acc1[8] = {0,0,0,0,0,0,0,0};
  float acc2[8] = {0,0,0,0,0,0,0,0};
  const float* pb1 = w1b + (size_t)j0 * 768 + m;
  const float* pb2 = w2b + (size_t)j0 * 768 + m;
  for (int jb = 0; jb < 192; jb += 4) {
    float F[4], Gp[4], Hh[4];
#pragma unroll
    for (int u = 0; u < 4; ++u) {
      float b1 = pb1[(size_t)(jb + u) * 768];
      float b2 = pb2[(size_t)(jb + u) * 768];
      F[u]  = b2 - 0.5f * b1;
      Gp[u] = 0.5f * b2 + 0.25f * b1;
      Hh[u] = 0.5f * b1;
    }
#pragma unroll
    for (int ii = 0; ii < 8; ++ii) {
      f32x4 c  = *(const f32x4*)&sC[ii][jb];
      f32x4 a1 = *(const f32x4*)&s1[ii][jb];
      f32x4 a2 = *(const f32x4*)&s2[ii][jb];
#pragma unroll
      for (int u = 0; u < 4; ++u) {
        acc1[ii] += c[u] * F[u];
        acc2[ii] += a1[u] * Gp[u] + a2[u] * Hh[u];
      }
    }
  }
  float* t1 = temp + ((size_t)jc * 768 + m) * 256 + i0;
  float* t2 = temp + ((size_t)(4 + jc) * 768 + m) * 256 + i0;
#pragma unroll
  for (int ii = 0; ii < 8; ++ii) { t1[ii] = acc1[ii]; t2[ii] = acc2[ii]; }
}

// ------------- fuse weights, stage 2: reduce j-chunks -> Bt f16 ------------
__global__ __launch_bounds__(256) void prep_B_convert(const float* __restrict__ temp,
                                                      unsigned short* __restrict__ Bt,
                                                      float* __restrict__ stats) {
  int idx = blockIdx.x * 256 + threadIdx.x;  // 0..196607
  int i = idx & 255;
  int m = idx >> 8;
  const float* t1 = temp + (size_t)m * 256 + i;
  const float* t2 = temp + ((size_t)4 * 768 + m) * 256 + i;
  float v1 = 0.f, v2 = 0.f;
#pragma unroll
  for (int jc = 0; jc < 4; ++jc) {
    v1 += t1[(size_t)jc * 768 * 256];
    v2 += t2[(size_t)jc * 768 * 256];
  }
  Bt[(size_t)m * KDIM + i]       = f2h(v1);
  Bt[(size_t)m * KDIM + 256 + i] = f2h(v2);
  if (idx < 1536) stats[idx] = 0.f;
}

// ---------------- main GEMM: out_pre = A @ B, + BN partial stats ------------
// 256x256 tile, BK=64, 512 thr = 8 waves (2 row-groups x 4 col-groups),
// mfma 16x16x32 f16, per-wave C = 128x64 (acc[8][4]).
// Schedule = catalog T3 "minimum" recipe: per K-tile {STAGE next tile into
// buf^1 FIRST; ds_read + 64 MFMA from buf; __syncthreads()}. One barrier and
// one (implicit) vmcnt(0) per K-tile, and the drain is cheap because the 8
// loads were issued ~400 cyc earlier, under the MFMA cluster. vs r3's 128^2
// 2-barrier loop this doubles MFMA-per-barrier, halves barrier count, cuts
// LDS-read traffic 0.75x (8x4 frag reuse), and quarters the block count.
// LDS = 128 KiB static (2 dbuf x (256x64 A + 256x64 B) f16), 1 block/CU.
// Swizzle (r1-verified, conflicts=0): rows are 128 B so the 16-B slot is the
// bank selector; slot ^= (row&7) on the ds_read side, and the SOURCE slot of
// global_load_lds is pre-swizzled (dest stays linear: both-sides-or-neither).
// XCD remap: 768 blocks = 8*96; each XCD owns 32 row-panels x 3 col-tiles
// consecutively (B is 0.75 MiB -> L2-resident; A-panels reused 3x back-to-back).
template <bool F16OUT>
__global__ __launch_bounds__(512, 2) void gemm_kernel(const unsigned short* __restrict__ A,
                                                      const unsigned short* __restrict__ Bt,
                                                      float* __restrict__ outf,
                                                      unsigned short* __restrict__ outh,
                                                      float* __restrict__ stats) {
  __shared__ __align__(16) unsigned short As[2 * 256 * 64];
  __shared__ __align__(16) unsigned short Bs[2 * 256 * 64];

  int bid = blockIdx.x;
  int swz = (bid & 7) * 96 + (bid >> 3);  // bijective: 768 % 8 == 0
  int bm  = swz % 3;             // col tile (M=768 -> 3)
  int bn  = swz / 3;             // row tile (N=65536 -> 256)
  int tid  = threadIdx.x;
  int wid  = tid >> 6;           // 0..7
  int lane = tid & 63;
  int quad = lane >> 4;
  int l15  = lane & 15;
  int wave_r = wid >> 2;         // 0..1  (row group: 128 rows each)
  int wave_c = wid & 3;          // 0..3  (col group: 64 cols each)

  size_t row0 = (size_t)bn * 256;
  int    col0 = bm * 256;

  f32x4 acc[8][4];
#pragma unroll
  for (int i = 0; i < 8; ++i)
#pragma unroll
    for (int j = 0; j < 4; ++j) acc[i][j] = (f32x4)(0.f);

  int rsub = lane >> 3;          // row within the wave's 8-row staging group
  int ssw  = (lane & 7) ^ rsub;  // pre-swizzled source slot (16-B units)

  // Wave-constant staging bases; the kt*64-short (128 B) step folds into the
  // 13-bit offset immediate; the i*64-row step is a base add.
  const unsigned short* gA0 = A  + (row0 + wid * 8 + rsub) * KDIM + ssw * 8;
  const unsigned short* gB0 = Bt + (size_t)(col0 + wid * 8 + rsub) * KDIM + ssw * 8;

#define STAGE(buf, kt)                                                              \
  do {                                                                              \
    _Pragma("unroll")                                                               \
    for (int i = 0; i < 4; ++i) {                                                   \
      int rl = i * 64 + wid * 8;                    /* wave-uniform row base */     \
      const unsigned short* gA = gA0 + (size_t)(i * 64) * KDIM + (kt) * 64;         \
      const unsigned short* gB = gB0 + (size_t)(i * 64) * KDIM + (kt) * 64;         \
      unsigned short* lA = As + (buf) * 16384 + rl * 64;   /* linear dest */        \
      unsigned short* lB = Bs + (buf) * 16384 + rl * 64;                            \
      __builtin_amdgcn_global_load_lds(                                             \
          (const __attribute__((address_space(1))) void*)(uintptr_t)gA,             \
          (__attribute__((address_space(3))) void*)(uint32_t)(uintptr_t)lA, 16, 0, 0); \
      __builtin_amdgcn_global_load_lds(                                             \
          (const __attribute__((address_space(1))) void*)(uintptr_t)gB,             \
          (__attribute__((address_space(3))) void*)(uint32_t)(uintptr_t)lB, 16, 0, 0); \
    }                                                                               \
  } while (0)

#define COMPUTE(buf)                                                                \
  do {                                                                              \
    _Pragma("unroll")                                                               \
    for (int ks = 0; ks < 2; ++ks) {                                                \
      f16x8 a[8], b[4];                                                             \
      _Pragma("unroll")                                                             \
      for (int rb = 0; rb < 8; ++rb) {                                              \
        int r  = wave_r * 128 + rb * 16 + l15;                                      \
        int sl = (ks * 4 + quad) ^ (l15 & 7);                                       \
        a[rb] = *(const f16x8*)&As[(buf) * 16384 + r * 64 + sl * 8];                \
      }                                                                             \
      _Pragma("unroll")                                                             \
      for (int cb = 0; cb < 4; ++cb) {                                              \
        int r  = wave_c * 64 + cb * 16 + l15;                                       \
        int sl = (ks * 4 + quad) ^ (l15 & 7);                                       \
        b[cb] = *(const f16x8*)&Bs[(buf) * 16384 + r * 64 + sl * 8];                \
      }                                                                             \
      __builtin_amdgcn_s_setprio(1);                                               \
      _Pragma("unroll")                                                             \
      for (int rb = 0; rb < 8; ++rb)                                                \
        _Pragma("unroll")                                                           \
        for (int cb = 0; cb < 4; ++cb)                                              \
          acc[rb][cb] = __builtin_amdgcn_mfma_f32_16x16x32_f16(a[rb], b[cb],        \
                                                               acc[rb][cb], 0, 0, 0); \
      __builtin_amdgcn_s_setprio(0);                                               \
    }                                                                               \
  } while (0)

  STAGE(0, 0);
  __syncthreads();
#pragma unroll
  for (int kt = 0; kt < 8; ++kt) {
    const int buf = kt & 1;
    if (kt < 7) STAGE(buf ^ 1, kt + 1);   // issue-early: loads fly under MFMAs
    COMPUTE(buf);
    if (kt < 7) __syncthreads();          // = vmcnt(0)+lgkmcnt(0)+barrier:
                                          // next tile landed, buf free to restage
  }
#undef STAGE
#undef COMPUTE

  // epilogue: store out_pre + per-column partial sums for BN (from fp32 accs)
#pragma unroll
  for (int cb = 0; cb < 4; ++cb) {
    int col = col0 + wave_c * 64 + cb * 16 + l15;
    float s1 = 0.f, s2 = 0.f;
#pragma unroll
    for (int rb = 0; rb < 8; ++rb) {
      size_t rg = row0 + wave_r * 128 + rb * 16 + quad * 4;
#pragma unroll
      for (int reg = 0; reg < 4; ++reg) {
        float v = acc[rb][cb][reg];
        if (F16OUT) outh[(rg + reg) * MDIM + col] = f2h(v);
        else        outf[(rg + reg) * MDIM + col] = v;
        s1 += v;
        s2 += v * v;
      }
    }
    s1 += __shfl_xor(s1, 16); s1 += __shfl_xor(s1, 32);
    s2 += __shfl_xor(s2, 16); s2 += __shfl_xor(s2, 32);
    if (quad == 0) {
      atomicAdd(&stats[col], s1);
      atomicAdd(&stats[768 + col], s2);
    }
  }
}

// ---------------- BN stats -> scale/shift ----------------------------------
__global__ void finalize_stats(const float* __restrict__ stats, const float* __restrict__ gamma,
                               const float* __restrict__ beta, float* __restrict__ ss) {
  int c = threadIdx.x;
  if (c < 768) {
    const float inv_n = 1.0f / 65536.0f;
    float mean = stats[c] * inv_n;
    float ex2  = stats[768 + c] * inv_n;
    float var  = ex2 - mean * mean;
    float scale = gamma[c] * rsqrtf(var + 1e-5f);
    ss[c]       = scale;
    ss[768 + c] = beta[c] - mean * scale;
  }
}

// ---------------- BN apply + sigmoid: f16 staging -> f32 out ---------------
__global__ __launch_bounds__(256) void bn_sigmoid_h(const unsigned short* __restrict__ outpre,
                                                    const float* __restrict__ ss,
                                                    float* __restrict__ out) {
  int idx = blockIdx.x * 256 + threadIdx.x;  // group of 8 halves
  int cg  = (idx % 96) * 8;
  f16x8 h = *(const f16x8*)(outpre + (size_t)idx * 8);
  float4 sc0 = *(const float4*)&ss[cg];
  float4 sc1 = *(const float4*)&ss[cg + 4];
  float4 sh0 = *(const float4*)&ss[768 + cg];
  float4 sh1 = *(const float4*)&ss[768 + cg + 4];
  float4 r0, r1;
  r0.x = 1.f / (1.f + __expf(-((float)h[0] * sc0.x + sh0.x)));
  r0.y = 1.f / (1.f + __expf(-((float)h[1] * sc0.y + sh0.y)));
  r0.z = 1.f / (1.f + __expf(-((float)h[2] * sc0.z + sh0.z)));
  r0.w = 1.f / (1.f + __expf(-((float)h[3] * sc0.w + sh0.w)));
  r1.x = 1.f / (1.f + __expf(-((float)h[4] * sc1.x + sh1.x)));
  r1.y = 1.f / (1.f + __expf(-((float)h[5] * sc1.y + sh1.y)));
  r1.z = 1.f / (1.f + __expf(-((float)h[6] * sc1.z + sh1.z)));
  r1.w = 1.f / (1.f + __expf(-((float)h[7] * sc1.w + sh1.w)));
  ((float4*)out)[(size_t)idx * 2]     = r0;
  ((float4*)out)[(size_t)idx * 2 + 1] = r1;
}

// ---------------- BN apply + sigmoid, in place fp32 (fallback) -------------
__global__ __launch_bounds__(256) void bn_sigmoid_f(float* __restrict__ out,
                                                    const float* __restrict__ ss) {
  int idx = blockIdx.x * 256 + threadIdx.x;  // float4 index
  int cg  = (idx % 192) * 4;
  float4 v  = ((const float4*)out)[idx];
  float4 sc = *(const float4*)&ss[cg];
  float4 sh = *(const float4*)&ss[768 + cg];
  v.x = 1.f / (1.f + __expf(-(v.x * sc.x + sh.x)));
  v.y = 1.f / (1.f + __expf(-(v.y * sc.y + sh.y)));
  v.z = 1.f / (1.f + __expf(-(v.z * sc.z + sh.z)));
  v.w = 1.f / (1.f + __expf(-(v.w * sc.w + sh.w)));
  ((float4*)out)[idx] = v;
}

extern "C" void kernel_launch(void* const* d_in, const int* in_sizes, int n_in,
                              void* d_out, int out_size, void* d_ws, size_t ws_size,
                              hipStream_t stream) {
  const float* x     = (const float*)d_in[0];
  const float* w1a   = (const float*)d_in[1];
  const float* w2a   = (const float*)d_in[2];
  const float* w1b   = (const float*)d_in[3];
  const float* w2b   = (const float*)d_in[4];
  const float* gamma = (const float*)d_in[5];
  const float* beta  = (const float*)d_in[6];
  float* out = (float*)d_out;

  // workspace layout
  size_t offA     = 0;
  size_t offBt    = offA + (size_t)NSAMP * KDIM * 2;            // 64 MiB
  size_t offTemp  = offBt + (size_t)MDIM * KDIM * 2;            // +0.75 MiB
  size_t offStats = offTemp + (size_t)2 * 4 * 768 * 256 * 4;    // +6 MiB
  size_t offSS    = offStats + 1536 * 4;
  size_t offOut   = (offSS + 1536 * 4 + 255) & ~(size_t)255;
  size_t needF16  = offOut + (size_t)NSAMP * MDIM * 2;          // ~167 MiB

  unsigned short* A    = (unsigned short*)((char*)d_ws + offA);
  unsigned short* Bt   = (unsigned short*)((char*)d_ws + offBt);
  float* temp          = (float*)((char*)d_ws + offTemp);
  float* stats         = (float*)((char*)d_ws + offStats);
  float* ss            = (float*)((char*)d_ws + offSS);
  unsigned short* oh   = (unsigned short*)((char*)d_ws + offOut);
  bool f16stage = ws_size >= needF16;

  prep_A_kernel<<<NSAMP * 64 / 256, 256, 0, stream>>>(x, A);
  prep_B_partial<<<384, 256, 0, stream>>>(w1a, w2a, w1b, w2b, temp);
  prep_B_convert<<<768, 256, 0, stream>>>(temp, Bt, stats);
  if (f16stage) {
    gemm_kernel<true><<<(NSAMP / 256) * (MDIM / 256), 512, 0, stream>>>(A, Bt, nullptr, oh, stats);
    finalize_stats<<<1, 768, 0, stream>>>(stats, gamma, beta, ss);
    bn_sigmoid_h<<<(size_t)NSAMP * MDIM / 8 / 256, 256, 0, stream>>>(oh, ss, out);
  } else {
    gemm_kernel<false><<<(NSAMP / 256) * (MDIM / 256), 512, 0, stream>>>(A, Bt, out, nullptr, stats);
    finalize_stats<<<1, 768, 0, stream>>>(stats, gamma, beta, ss);
    bn_sigmoid_f<<<(size_t)NSAMP * MDIM / 4 / 256, 256, 0, stream>>>(out, ss);
  }
}